// Round 6
// baseline (274.278 us; speedup 1.0000x reference)
//
#include <hip/hip_runtime.h>

#define HWD 224
#define NPP 3136              // 56*56 patches per image
#define WPD 56
#define EDIM 128
#define NCLS 20
#define NPATCH 200704
#define NOUT (NPATCH*EDIM)
#define TPW 4                 // 32-patch tiles per wave
#define NBLK (NPATCH/(32*TPW))  // 1568 one-wave blocks

typedef float  f32x16 __attribute__((ext_vector_type(16)));
typedef int    i32x4  __attribute__((ext_vector_type(4)));
typedef __bf16 bf16x8 __attribute__((ext_vector_type(8)));

static __device__ __forceinline__ unsigned bfpair(float a, float b) {
    unsigned ua = __float_as_uint(a), ub = __float_as_uint(b);
    ua = (ua + 0x7fffu + ((ua >> 16) & 1u)) >> 16;          // RNE, low half
    ub = (ub + 0x7fffu + ((ub >> 16) & 1u)) & 0xffff0000u;  // RNE, high half
    return ua | ub;
}
static __device__ __forceinline__ bf16x8 pack8(float4 lo, float4 hi) {
    i32x4 v;
    v.x = bfpair(lo.x, lo.y); v.y = bfpair(lo.z, lo.w);
    v.z = bfpair(hi.x, hi.y); v.w = bfpair(hi.z, hi.w);
    return __builtin_bit_cast(bf16x8, v);
}

struct Pix { float4 r[6]; i32x4 m[2]; int p; };

static __device__ __forceinline__ Pix load_pix(const float* __restrict__ rgb,
                                               const int* __restrict__ mask,
                                               int tile, int pt, int hi) {
    Pix o;
    o.p = tile * 32 + pt;
    const int b  = o.p / NPP;
    const int r  = o.p - b * NPP;
    const int hp = r / WPD;
    const int wp = r - hp * WPD;
    const int row = hp * 4 + hi * 2;              // this lane's 2 pixel rows
    const float* base = rgb + ((size_t)(b * 3) * HWD + row) * HWD + wp * 4;
#pragma unroll
    for (int s = 0; s < 3; ++s) {
        o.r[2*s]   = *(const float4*)(base + (size_t)s * HWD * HWD);
        o.r[2*s+1] = *(const float4*)(base + (size_t)s * HWD * HWD + HWD);
    }
    const int* mb = mask + ((size_t)b * HWD + row) * HWD + wp * 4;
    o.m[0] = *(const i32x4*)(mb);
    o.m[1] = *(const i32x4*)(mb + HWD);
    return o;
}

// One wave/block, 32x32x16 MFMA: wave tile = 32 patches x 128 ch (4 ch-tiles).
// A=W (row=channel=lane&31, k=hi*8+i), B=X (col=patch=lane&31, same k labels
// -> any HW k-permutation cancels). C/D: col=patch, row=rr+8q+4hi: reg-quads
// are 4 CONSECUTIVE channels -> float4 stores; lane owns one patch -> LN and
// hist each need a single shfl_xor(32); argmax fully lane-local.
__global__ __launch_bounds__(64)
__attribute__((amdgpu_waves_per_eu(2, 2)))
void fused_patch_embed_mfma32(
    const float* __restrict__ rgb, const int* __restrict__ mask,
    const float* __restrict__ wgt, const float* __restrict__ pb,
    const float* __restrict__ gam, const float* __restrict__ bet,
    const float* __restrict__ sem, const float* __restrict__ cw,
    float* __restrict__ out, int out_size)
{
    const int lane = (int)threadIdx.x;
    const int pt = lane & 31;      // patch-in-tile (A/B col, C col)
    const int hi = lane >> 5;      // k-half / channel-row offset

    // ---- persistent A fragments: W[128][64] -> 16 bf16x8 (64 VGPR) ----
    bf16x8 aw[4][4];
#pragma unroll
    for (int t = 0; t < 4; ++t) {
#pragma unroll
        for (int s = 0; s < 4; ++s) {
            const float* wr = wgt + (size_t)(t * 32 + pt) * 64 + s * 16 + hi * 8;
            aw[t][s] = pack8(*(const float4*)wr, *(const float4*)(wr + 4));
        }
    }
    float cwv[NCLS];
#pragma unroll
    for (int c = 0; c < NCLS; ++c) cwv[c] = cw[c];   // uniform -> scalarizable

    const int tile0 = (int)blockIdx.x * TPW;
    Pix px[2];
    px[0] = load_pix(rgb, mask, tile0, pt, hi);

#pragma unroll
    for (int ti = 0; ti < TPW; ++ti) {
        if (ti + 1 < TPW)
            px[(ti + 1) & 1] = load_pix(rgb, mask, tile0 + ti + 1, pt, hi);
        const Pix c = px[ti & 1];

        // ---- B fragments (this lane's patch, its 2 rows per channel) ----
        bf16x8 bx[4];
        bx[0] = pack8(c.r[0], c.r[1]);
        bx[1] = pack8(c.r[2], c.r[3]);
        bx[2] = pack8(c.r[4], c.r[5]);
        const float4 mf0 = make_float4((float)c.m[0].x, (float)c.m[0].y,
                                       (float)c.m[0].z, (float)c.m[0].w);
        const float4 mf1 = make_float4((float)c.m[1].x, (float)c.m[1].y,
                                       (float)c.m[1].z, (float)c.m[1].w);
        bx[3] = pack8(mf0, mf1);

        // ---- 16 MFMAs: acc[t] = bias + W*X^T ----
        f32x16 acc[4];
#pragma unroll
        for (int t = 0; t < 4; ++t) {
            f32x16 a;
#pragma unroll
            for (int q = 0; q < 4; ++q) {
                const float4 pv = *(const float4*)(pb + t * 32 + 8 * q + 4 * hi);
                a[4*q+0] = pv.x; a[4*q+1] = pv.y; a[4*q+2] = pv.z; a[4*q+3] = pv.w;
            }
#pragma unroll
            for (int s = 0; s < 4; ++s)
                a = __builtin_amdgcn_mfma_f32_32x32x16_bf16(aw[t][s], bx[s], a, 0, 0, 0);
            acc[t] = a;
        }

        // ---- LN stats: lane holds 64 of 128 channels of its patch ----
        float ss = 0.f, qq = 0.f;
#pragma unroll
        for (int t = 0; t < 4; ++t)
#pragma unroll
            for (int e = 0; e < 16; ++e) { const float v = acc[t][e]; ss += v; qq = fmaf(v, v, qq); }
        ss += __shfl_xor(ss, 32, 64);
        qq += __shfl_xor(qq, 32, 64);
        const float mu   = ss * (1.f / EDIM);
        const float rstd = rsqrtf(qq * (1.f / EDIM) - mu * mu + 1e-5f);

        // ---- weighted histogram (8 px/lane) + lane-local argmax ----
        unsigned pk0 = 0, pk1 = 0, pk2 = 0, pk3 = 0;
#define CNT1(val) { const unsigned v = (unsigned)(val) & 31u;                   \
                    const unsigned qw = (v * 43u) >> 8;                         \
                    const unsigned bit = 1u << (5u * (v - 6u * qw));            \
                    pk0 += (qw == 0u) ? bit : 0u; pk1 += (qw == 1u) ? bit : 0u; \
                    pk2 += (qw == 2u) ? bit : 0u; pk3 += (qw == 3u) ? bit : 0u; }
        CNT1(c.m[0].x) CNT1(c.m[0].y) CNT1(c.m[0].z) CNT1(c.m[0].w)
        CNT1(c.m[1].x) CNT1(c.m[1].y) CNT1(c.m[1].z) CNT1(c.m[1].w)
#undef CNT1
        pk0 += __shfl_xor(pk0, 32, 64); pk1 += __shfl_xor(pk1, 32, 64);
        pk2 += __shfl_xor(pk2, 32, 64); pk3 += __shfl_xor(pk3, 32, 64);
        float bs = -1.f; int best = 0;
#pragma unroll
        for (int cc = 0; cc < NCLS; ++cc) {
            const unsigned word = (cc < 6) ? pk0 : (cc < 12) ? pk1 : (cc < 18) ? pk2 : pk3;
            const unsigned cnt = (word >> (5 * (cc % 6))) & 31u;
            const float sc = (float)cnt * cwv[cc];
            if (sc > bs) { bs = sc; best = cc; }     // ascending cc => first max
        }

        // ---- LN apply + sem add + float4 stores (lane's own patch row) ----
        const float* sr = sem + (size_t)best * EDIM + 4 * hi;
        float* op = out + (size_t)c.p * EDIM + 4 * hi;
#pragma unroll
        for (int t = 0; t < 4; ++t) {
#pragma unroll
            for (int q = 0; q < 4; ++q) {
                const int off = t * 32 + 8 * q;
                const float4 g4 = *(const float4*)(gam + off + 4 * hi);
                const float4 b4 = *(const float4*)(bet + off + 4 * hi);
                const float4 s4 = *(const float4*)(sr + off);
                float4 o;
                o.x = fmaf((acc[t][4*q+0] - mu) * rstd, g4.x, b4.x) + s4.x;
                o.y = fmaf((acc[t][4*q+1] - mu) * rstd, g4.y, b4.y) + s4.y;
                o.z = fmaf((acc[t][4*q+2] - mu) * rstd, g4.z, b4.z) + s4.z;
                o.w = fmaf((acc[t][4*q+3] - mu) * rstd, g4.w, b4.w) + s4.w;
                *(float4*)(op + off) = o;
            }
        }
    }

    // tuple second output (Hp, Wp) if the harness appended it
    if (blockIdx.x == 0 && lane == 0) {
        for (int i = NOUT; i < out_size; ++i) out[i] = 56.0f;
    }
}

extern "C" void kernel_launch(void* const* d_in, const int* in_sizes, int n_in,
                              void* d_out, int out_size, void* d_ws, size_t ws_size,
                              hipStream_t stream) {
    const float* rgb  = (const float*)d_in[0];
    const int*   mask = (const int*)d_in[1];
    const float* wgt  = (const float*)d_in[2];
    const float* pb   = (const float*)d_in[3];
    const float* gam  = (const float*)d_in[4];
    const float* bet  = (const float*)d_in[5];
    const float* sem  = (const float*)d_in[6];
    const float* cw   = (const float*)d_in[7];
    float* out = (float*)d_out;

    fused_patch_embed_mfma32<<<NBLK, 64, 0, stream>>>(rgb, mask, wgt, pb, gam, bet,
                                                      sem, cw, out, out_size);
}